// Round 1
// baseline (237.989 us; speedup 1.0000x reference)
//
#include <hip/hip_runtime.h>

#define BB 16
#define NN 38400
#define DD 64
#define SS 7

__device__ __forceinline__ float wsum64(float v) {
#pragma unroll
  for (int off = 32; off > 0; off >>= 1) v += __shfl_xor(v, off);
  return v;
}

// ---------------------------------------------------------------------------
// Slot-side kernel: 112 blocks (one per (b,s)), 64 threads (lane = d).
// mode 0: init slots from mu/log_sigma/slots_init, then tail
// mode 1: GRU + MLP update from accumulators, then tail
// mode 2: GRU + MLP update, write final slots to d_out, no tail
// tail: LN_slot -> q -> qk (scale folded) -> gqk = g_in*qk, sgq, cb;
//       zero ACC/ACCM/Z for the upcoming main kernel.
// ---------------------------------------------------------------------------
__global__ __launch_bounds__(64) void k_slot(
    int mode,
    const float* __restrict__ slots_init, const float* __restrict__ mu,
    const float* __restrict__ lsig,
    const float* __restrict__ ln_slot_g, const float* __restrict__ ln_slot_b,
    const float* __restrict__ ln_mlp_g, const float* __restrict__ ln_mlp_b,
    const float* __restrict__ ln_in_g, const float* __restrict__ ln_in_b,
    const float* __restrict__ Wq, const float* __restrict__ Wk,
    const float* __restrict__ Wv,
    const float* __restrict__ W_ih, const float* __restrict__ W_hh,
    const float* __restrict__ b_ih, const float* __restrict__ b_hh,
    const float* __restrict__ W1, const float* __restrict__ b1,
    const float* __restrict__ W2, const float* __restrict__ b2,
    float* __restrict__ slots, float* __restrict__ gqk,
    float* __restrict__ sc,
    float* __restrict__ ACC, float* __restrict__ ACCM, float* __restrict__ Zg,
    float* __restrict__ out)
{
  const int bs = blockIdx.x;
  const int b = bs / SS, s = bs % SS;
  const int d = threadIdx.x;
  __shared__ float t0[64], t1[64], hh[128];

  float slot;
  if (mode == 0) {
    slot = mu[d] + __expf(lsig[d]) * slots_init[bs * 64 + d];
  } else {
    // updates = ((g_in*(ACC-ACCM) + b_in*Z)/Z) @ Wv^T
    const float zv = Zg[b * 8 + s];
    const float am = ACCM[b * 8 + s];
    const float ac = ACC[(b * 8 + s) * 64 + d];
    const float ubar = (ln_in_g[d] * (ac - am) + ln_in_b[d] * zv) / zv;
    t0[d] = ubar;
    __syncthreads();
    float upd = 0.f;
#pragma unroll
    for (int e = 0; e < 64; ++e) upd += t0[e] * Wv[d * 64 + e];
    const float sp = slots[bs * 64 + d];
    __syncthreads();
    t0[d] = upd;
    t1[d] = sp;
    __syncthreads();
    // GRU gates (torch order r,z,n)
    float s_r = b_ih[d] + b_hh[d];
    float s_z = b_ih[64 + d] + b_hh[64 + d];
    float i_n = b_ih[128 + d];
    float h_n = b_hh[128 + d];
#pragma unroll
    for (int e = 0; e < 64; ++e) {
      const float u = t0[e], p = t1[e];
      s_r += u * W_ih[d * 64 + e] + p * W_hh[d * 64 + e];
      s_z += u * W_ih[(64 + d) * 64 + e] + p * W_hh[(64 + d) * 64 + e];
      i_n += u * W_ih[(128 + d) * 64 + e];
      h_n += p * W_hh[(128 + d) * 64 + e];
    }
    const float rg = 1.f / (1.f + __expf(-s_r));
    const float zg = 1.f / (1.f + __expf(-s_z));
    const float ng = tanhf(i_n + rg * h_n);
    const float hv = (1.f - zg) * ng + zg * sp;
    // residual MLP
    const float mn = wsum64(hv) * (1.f / 64.f);
    const float dv = hv - mn;
    const float vr = wsum64(dv * dv) * (1.f / 64.f);
    const float rs = rsqrtf(vr + 1e-5f);
    const float mld = dv * rs * ln_mlp_g[d] + ln_mlp_b[d];
    __syncthreads();
    t0[d] = mld;
    __syncthreads();
    float h0 = b1[d], h1 = b1[64 + d];
#pragma unroll
    for (int e = 0; e < 64; ++e) {
      const float m = t0[e];
      h0 += m * W1[d * 64 + e];
      h1 += m * W1[(64 + d) * 64 + e];
    }
    hh[d] = fmaxf(h0, 0.f);
    hh[64 + d] = fmaxf(h1, 0.f);
    __syncthreads();
    float o = hv + b2[d];
#pragma unroll
    for (int j = 0; j < 128; ++j) o += hh[j] * W2[d * 128 + j];
    slot = o;
  }

  if (mode == 2) {
    out[bs * 64 + d] = slot;
    return;
  }
  slots[bs * 64 + d] = slot;

  // tail: compute gqk / sgq / cb for next main pass
  const float mn = wsum64(slot) * (1.f / 64.f);
  const float dv = slot - mn;
  const float vr = wsum64(dv * dv) * (1.f / 64.f);
  const float rs = rsqrtf(vr + 1e-5f);
  const float sln = dv * rs * ln_slot_g[d] + ln_slot_b[d];
  __syncthreads();
  t0[d] = sln;
  __syncthreads();
  float q = 0.f;
#pragma unroll
  for (int e = 0; e < 64; ++e) q += t0[e] * Wq[d * 64 + e];
  __syncthreads();
  t1[d] = q;
  __syncthreads();
  float qe = 0.f;  // lane d plays role of e here
#pragma unroll
  for (int dd = 0; dd < 64; ++dd) qe += t1[dd] * Wk[dd * 64 + d];
  qe *= 0.125f;  // scale = D^-0.5
  const float gq = ln_in_g[d] * qe;
  gqk[(b * 8 + s) * 64 + d] = gq;
  const float sg = wsum64(gq);
  const float cb = wsum64(ln_in_b[d] * qe);
  if (d == 0) {
    sc[(b * 8 + s) * 2 + 0] = sg;
    sc[(b * 8 + s) * 2 + 1] = cb;
  }
  // zero accumulators for upcoming main kernel
  ACC[(b * 8 + s) * 64 + d] = 0.f;
  if (d == 0) {
    ACCM[b * 8 + s] = 0.f;
    Zg[b * 8 + s] = 0.f;
  }
}

// ---------------------------------------------------------------------------
// Main kernel: grid (150, 16), 256 threads. One 256-row tile per block.
// Phase 1: thread-per-row — load row (16 x float4), LN stats, 7 dots vs
//          block-uniform gqk (scalar loads), softmax over 7 slots, stash
//          p*rstd in LDS; wave-reduce Z and ACCM partials.
// Phase 2: thread = (s,d) — outer-product accumulate ACC[s,d] from broadcast
//          LDS reads + coalesced (L1/L2-hot) x re-reads; one atomicAdd each.
// ---------------------------------------------------------------------------
__global__ __launch_bounds__(256) void k_main(
    const float* __restrict__ x,
    const float* __restrict__ gqk,  // [B][8][64] (g_in ⊙ scale·Wk^T q)
    const float* __restrict__ sc,   // [B][8][2]  (sgq, cb)
    float* __restrict__ ACC, float* __restrict__ ACCM, float* __restrict__ Zg)
{
  __shared__ __align__(16) float aa[8][256];
  __shared__ float wz[4][8], wm[4][8];
  const int t = threadIdx.x;
  const int b = blockIdx.y;
  const int row0 = blockIdx.x * 256;
  const float4* xr4 =
      reinterpret_cast<const float4*>(x + ((size_t)b * NN + row0 + t) * 64);

  const float* qb = gqk + b * 512;
  const float* scb = sc + b * 16;

  float lg[7];
#pragma unroll
  for (int s2 = 0; s2 < 7; ++s2) lg[s2] = 0.f;
  float sum = 0.f, sq = 0.f;
#pragma unroll
  for (int k = 0; k < 16; ++k) {
    const float4 v = xr4[k];
    sum += v.x + v.y + v.z + v.w;
    sq += v.x * v.x + v.y * v.y + v.z * v.z + v.w * v.w;
#pragma unroll
    for (int s2 = 0; s2 < 7; ++s2) {
      lg[s2] += v.x * qb[s2 * 64 + 4 * k + 0];
      lg[s2] += v.y * qb[s2 * 64 + 4 * k + 1];
      lg[s2] += v.z * qb[s2 * 64 + 4 * k + 2];
      lg[s2] += v.w * qb[s2 * 64 + 4 * k + 3];
    }
  }
  const float mean = sum * (1.f / 64.f);
  const float var = sq * (1.f / 64.f) - mean * mean;
  const float rstd = rsqrtf(var + 1e-5f);
  const float rm = rstd * mean;

  float mx = -1e30f;
#pragma unroll
  for (int s2 = 0; s2 < 7; ++s2) {
    lg[s2] = rstd * lg[s2] - rm * scb[s2 * 2] + scb[s2 * 2 + 1];
    mx = fmaxf(mx, lg[s2]);
  }
  float se = 0.f, ex[7];
#pragma unroll
  for (int s2 = 0; s2 < 7; ++s2) {
    ex[s2] = __expf(lg[s2] - mx);
    se += ex[s2];
  }
  const float inv = 1.f / se;
#pragma unroll
  for (int s2 = 0; s2 < 7; ++s2) {
    const float p = ex[s2] * inv + 1e-8f;  // softmax + EPS
    aa[s2][t] = p * rstd;
    ex[s2] = p;
  }
  aa[7][t] = 0.f;

  // block partials for Z[s] and ACCM[s]
#pragma unroll
  for (int s2 = 0; s2 < 7; ++s2) {
    float z = ex[s2];
    float a = ex[s2] * rm;  // p * rstd * mean
#pragma unroll
    for (int off = 32; off > 0; off >>= 1) {
      z += __shfl_xor(z, off);
      a += __shfl_xor(a, off);
    }
    if ((t & 63) == 0) {
      wz[t >> 6][s2] = z;
      wm[t >> 6][s2] = a;
    }
  }
  __syncthreads();
  if (t < 7) {
    atomicAdd(&Zg[b * 8 + t], wz[0][t] + wz[1][t] + wz[2][t] + wz[3][t]);
    atomicAdd(&ACCM[b * 8 + t], wm[0][t] + wm[1][t] + wm[2][t] + wm[3][t]);
  }

  // phase 2: outer product ACC[s][d] += sum_n (p*rstd)[n][s] * x[n][d]
  const int d = t & 63;
  const int s0 = t >> 6;      // 0..3
  const int s1 = s0 + 4;      // 4..7 (7 = dummy, aa[7][*]==0)
  const float* xc = x + ((size_t)b * NN + row0) * 64 + d;
  float acc0 = 0.f, acc1 = 0.f;
#pragma unroll 4
  for (int n4 = 0; n4 < 64; ++n4) {
    const float4 p0 = *reinterpret_cast<const float4*>(&aa[s0][n4 * 4]);
    const float4 p1 = *reinterpret_cast<const float4*>(&aa[s1][n4 * 4]);
    const float x0 = xc[(n4 * 4 + 0) * 64];
    const float x1 = xc[(n4 * 4 + 1) * 64];
    const float x2 = xc[(n4 * 4 + 2) * 64];
    const float x3 = xc[(n4 * 4 + 3) * 64];
    acc0 += p0.x * x0;
    acc1 += p1.x * x0;
    acc0 += p0.y * x1;
    acc1 += p1.y * x1;
    acc0 += p0.z * x2;
    acc1 += p1.z * x2;
    acc0 += p0.w * x3;
    acc1 += p1.w * x3;
  }
  atomicAdd(&ACC[(b * 8 + s0) * 64 + d], acc0);
  atomicAdd(&ACC[(b * 8 + s1) * 64 + d], acc1);
}

extern "C" void kernel_launch(void* const* d_in, const int* in_sizes, int n_in,
                              void* d_out, int out_size, void* d_ws,
                              size_t ws_size, hipStream_t stream) {
  const float* inputs     = (const float*)d_in[0];
  const float* slots_init = (const float*)d_in[1];
  const float* slots_mu   = (const float*)d_in[2];
  const float* slots_lsig = (const float*)d_in[3];
  const float* ln_in_g    = (const float*)d_in[4];
  const float* ln_in_b    = (const float*)d_in[5];
  const float* ln_slot_g  = (const float*)d_in[6];
  const float* ln_slot_b  = (const float*)d_in[7];
  const float* ln_mlp_g   = (const float*)d_in[8];
  const float* ln_mlp_b   = (const float*)d_in[9];
  const float* Wq   = (const float*)d_in[10];
  const float* Wk   = (const float*)d_in[11];
  const float* Wv   = (const float*)d_in[12];
  const float* W_ih = (const float*)d_in[13];
  const float* W_hh = (const float*)d_in[14];
  const float* b_ih = (const float*)d_in[15];
  const float* b_hh = (const float*)d_in[16];
  const float* W1   = (const float*)d_in[17];
  const float* b1   = (const float*)d_in[18];
  const float* W2   = (const float*)d_in[19];
  const float* b2   = (const float*)d_in[20];

  float* ws    = (float*)d_ws;
  float* slots = ws;            // B*S*64 = 7168
  float* gqk   = ws + 7168;     // B*8*64 = 8192
  float* sc    = gqk + 8192;    // B*8*2  = 256
  float* ACC   = sc + 256;      // B*8*64 = 8192
  float* ACCM  = ACC + 8192;    // B*8    = 128
  float* Zg    = ACCM + 128;    // B*8    = 128

  float* out = (float*)d_out;

#define SLOT_ARGS                                                          \
  slots_init, slots_mu, slots_lsig, ln_slot_g, ln_slot_b, ln_mlp_g,        \
      ln_mlp_b, ln_in_g, ln_in_b, Wq, Wk, Wv, W_ih, W_hh, b_ih, b_hh, W1,  \
      b1, W2, b2, slots, gqk, sc, ACC, ACCM, Zg, out

  k_slot<<<112, 64, 0, stream>>>(0, SLOT_ARGS);
  for (int it = 0; it < 3; ++it) {
    k_main<<<dim3(150, 16), 256, 0, stream>>>(inputs, gqk, sc, ACC, ACCM, Zg);
    k_slot<<<112, 64, 0, stream>>>(it == 2 ? 2 : 1, SLOT_ARGS);
  }
#undef SLOT_ARGS
}